// Round 3
// baseline (2042.531 us; speedup 1.0000x reference)
//
#include <hip/hip_runtime.h>

// Fused Conv1d(k=3,pad=1) + BN(inference) + 4-step LIF + residual.
// x: (L=2048, TB=128, D=128) f32. conv_w: (D,D,3). out: (L,TB,D) f32.
//
// R3: LDS-pipe-bound fix. x conv reads = wave-uniform global 16B loads (L1,
// one line per request, no LDS, no broadcast cost). Weights: 12KB LDS tile,
// conflict-free b32 layout wst[(iloc*3+k)][o]. it-loop outer, t-loop inner,
// acc[4][16] in VGPRs -> 32 barriers/block (was 128). LIF state only live in
// epilogue. FMA order bitwise-identical to R2 (absmax 0.0 preserved).

constexpr int L   = 2048;
constexpr int NTB = 128;
constexpr int D   = 128;
constexpr int T   = 4;
constexpr int JT  = 16;          // l-positions per thread
constexpr int LT  = 32;          // l-tile per block (2 halves x JT)
constexpr int NIT = 16;          // number of i-tiles
constexpr int IT  = 8;           // input channels per tile
constexpr int NROW = JT + 2;     // staged row pointers (halo)

__device__ __forceinline__ float4 scale4(float4 v, float m) {
    return make_float4(v.x * m, v.y * m, v.z * m, v.w * m);
}

__global__ __launch_bounds__(256, 4)
void snn_conv_lif(const float* __restrict__ x, const float* __restrict__ w,
                  const float* __restrict__ gamma, const float* __restrict__ beta,
                  const float* __restrict__ mean, const float* __restrict__ var,
                  float* __restrict__ out) {
    __shared__ float wst[IT * 3 * D];   // [(iloc*3+k)][o], 12288 B, conflict-free

    const int tid = threadIdx.x;
    const int b   = blockIdx.x & 31;
    const int lt  = blockIdx.x >> 5;
    const int l0  = lt * LT;
    const int o   = tid & 127;          // output channel
    const int lh  = tid >> 7;           // l half
    const int p0  = lh * JT;
    const int p0u = __builtin_amdgcn_readfirstlane(p0);  // wave-uniform -> SGPR rows

    // Wave-uniform row pointers x[l0+p0-1+p][.][b*D ...], clamped at edges.
    const float* xrow[NROW];
    float rmask[NROW];
    #pragma unroll
    for (int p = 0; p < NROW; ++p) {
        const int l = l0 + p0u - 1 + p;
        const bool valid = (l >= 0) && (l < L);
        xrow[p]  = x + (size_t)(valid ? l : 0) * (NTB * D) + b * D;
        rmask[p] = valid ? 1.f : 0.f;
    }
    const float m0  = rmask[0];
    const float m17 = rmask[NROW - 1];

    const float sc = gamma[o] / sqrtf(var[o] + 1e-5f);
    const float bi = beta[o] - mean[o] * sc;

    float acc[T][JT];
    #pragma unroll
    for (int t = 0; t < T; ++t)
        #pragma unroll
        for (int j = 0; j < JT; ++j) acc[t][j] = 0.f;

    for (int it = 0; it < NIT; ++it) {
        __syncthreads();
        {   // stage weight tile: thread (o, lh) loads 12 floats, writes conflict-free
            const float4* wp = (const float4*)(w + o * (D * 3) + it * (IT * 3) + lh * 12);
            const float4 w0 = wp[0], w1 = wp[1], w2 = wp[2];
            float* dst = wst + lh * 12 * D + o;
            dst[0 * D] = w0.x; dst[1 * D]  = w0.y; dst[2 * D]  = w0.z; dst[3 * D]  = w0.w;
            dst[4 * D] = w1.x; dst[5 * D]  = w1.y; dst[6 * D]  = w1.z; dst[7 * D]  = w1.w;
            dst[8 * D] = w2.x; dst[9 * D]  = w2.y; dst[10 * D] = w2.z; dst[11 * D] = w2.w;
        }
        __syncthreads();

        #pragma unroll
        for (int i4 = 0; i4 < 2; ++i4) {
            float wr[12];   // wr[iq*3+k] = w[o][it*8+i4*4+iq][k] — same order as R2
            #pragma unroll
            for (int f = 0; f < 12; ++f) wr[f] = wst[(i4 * 12 + f) * D + o];
            const int ic = it * IT + i4 * 4;

            #pragma unroll
            for (int t = 0; t < T; ++t) {
                const int coff = t * 32 * D + ic;   // + n*D + i (b*D folded in xrow)
                float4 xa = scale4(*(const float4*)(xrow[0] + coff), m0);
                float4 xb = *(const float4*)(xrow[1] + coff);
                #pragma unroll
                for (int j = 0; j < JT; ++j) {
                    float4 xc = *(const float4*)(xrow[j + 2] + coff);
                    if (j == JT - 1) xc = scale4(xc, m17);
                    float s = acc[t][j];
                    s = fmaf(xa.x, wr[0], s);  // k0 i0
                    s = fmaf(xa.y, wr[3], s);  // k0 i1
                    s = fmaf(xa.z, wr[6], s);  // k0 i2
                    s = fmaf(xa.w, wr[9], s);  // k0 i3
                    s = fmaf(xb.x, wr[1], s);  // k1 i0
                    s = fmaf(xb.y, wr[4], s);
                    s = fmaf(xb.z, wr[7], s);
                    s = fmaf(xb.w, wr[10], s);
                    s = fmaf(xc.x, wr[2], s);  // k2 i0
                    s = fmaf(xc.y, wr[5], s);
                    s = fmaf(xc.z, wr[8], s);
                    s = fmaf(xc.w, wr[11], s);
                    acc[t][j] = s;
                    xa = xb; xb = xc;
                }
            }
        }
    }

    // ---- BN + LIF + residual + store (v only live here) ----
    float v[JT];
    #pragma unroll
    for (int j = 0; j < JT; ++j) v[j] = 0.f;
    #pragma unroll
    for (int t = 0; t < T; ++t) {
        const int n = t * 32 + b;
        #pragma unroll
        for (int j = 0; j < JT; ++j) {
            const float y = fmaf(acc[t][j], sc, bi);
            const float h = 0.5f * (v[j] + y);      // v + (y - v)/tau, tau=2
            const bool fire = (h >= 1.0f);
            v[j] = fire ? 0.f : h;                  // hard reset
            const float s = fire ? 1.f : 0.f;
            const float xv = xrow[j + 1][t * 32 * D + o];   // residual (row always valid)
            out[(l0 + p0 + j) * (NTB * D) + n * D + o] = xv + s;
        }
    }
}

extern "C" void kernel_launch(void* const* d_in, const int* in_sizes, int n_in,
                              void* d_out, int out_size, void* d_ws, size_t ws_size,
                              hipStream_t stream) {
    const float* x     = (const float*)d_in[0];
    const float* w     = (const float*)d_in[1];
    const float* gamma = (const float*)d_in[2];
    const float* beta  = (const float*)d_in[3];
    const float* mean  = (const float*)d_in[4];
    const float* var   = (const float*)d_in[5];
    float* out = (float*)d_out;

    dim3 grid((L / LT) * 32);   // 64 l-tiles x 32 b = 2048 blocks
    dim3 block(256);
    snn_conv_lif<<<grid, block, 0, stream>>>(x, w, gamma, beta, mean, var, out);
}